// Round 12
// baseline (154.415 us; speedup 1.0000x reference)
//
#include <hip/hip_runtime.h>
#include <math.h>

#define B_  4096
#define C_  64
#define LQ_ 32
#define D_  128
#define H_  192

typedef __attribute__((ext_vector_type(8))) short bf16x8;
typedef __attribute__((ext_vector_type(4))) float f32x4;

#define KEEP(x) asm volatile("" : "+v"(x))

__device__ inline unsigned cvt_pk_bf16(float lo, float hi) {
    unsigned r;
    asm("v_cvt_pk_bf16_f32 %0, %1, %2" : "=v"(r) : "v"(lo), "v"(hi));
    return r;
}
__device__ inline short f2b(float x) { return (short)(cvt_pk_bf16(x, x) & 0xffff); }
__device__ inline float sigm(float x) { return 1.f / (1.f + __expf(-x)); }

// Raw barrier: waits LDS ops only; leaves global loads in flight (T4).
__device__ inline void wg_barrier() {
    asm volatile("s_waitcnt lgkmcnt(0)" ::: "memory");
    __builtin_amdgcn_s_barrier();
    asm volatile("" ::: "memory");
}

// ---------------------------------------------------------------------------
// Prep: transpose + convert weights to bf16.
// ---------------------------------------------------------------------------
__global__ __launch_bounds__(256) void prep_kernel(
    const float* __restrict__ W1, const float* __restrict__ W2,
    const float* __restrict__ Wx, const float* __restrict__ Wh,
    short* __restrict__ W1T, short* __restrict__ W2T, short* __restrict__ WTl)
{
    int idx = blockIdx.x * 256 + threadIdx.x;   // 0 .. 131071
    if (idx < 192 * 256) {
        int j = idx >> 8, k = idx & 255;
        W1T[idx] = f2b(W1[k * H_ + j]);
    }
    if (idx < 128 * 192) {
        int j = idx / 192, k = idx - j * 192;
        W2T[idx] = f2b(W2[k * D_ + j]);
    }
    if (idx < 512 * 256) {
        int p = idx >> 8, k = idx & 255;
        int w = p >> 6, g = (p >> 4) & 3, jj = p & 15;
        int jo = g * 128 + w * 16 + jj;
        float v = (k < 128) ? Wx[k * 512 + jo] : Wh[(k - 128) * 512 + jo];
        WTl[idx] = f2b(v);
    }
}

// ---------------------------------------------------------------------------
// Table encoder v11: LSTM-profile bodies.
//  - 256 blocks x 512 thr (8 waves), 16 b's per block, ONE b (64 rows) per
//    body -> 72 MFMA per 2 barriers (4x better amortization than 16-row chunks)
//  - ALL weights pinned in regs/AGPRs -> ZERO global traffic in the loop
//    except the input stream itself.
//  - reg-staged bf16 LDS (flat dbuf), depth-1 prefetch issued a full body
//    ahead; per-b csum flushed barrier-free; single epilogue.
// Body(b): GEMM1(b)->h | stage flat(b+1), issue pf(b+2) | barA |
//          GEMM2(b)+csum+flush | barB.
// ---------------------------------------------------------------------------
__global__ __launch_bounds__(512) __attribute__((amdgpu_waves_per_eu(2, 2)))
void table_kernel(
    const float* __restrict__ header, const float* __restrict__ tword,
    const float* __restrict__ masks, const int* __restrict__ num_cols,
    const short* __restrict__ W1T, const float* __restrict__ b1,
    const short* __restrict__ W2T, const float* __restrict__ b2,
    float* __restrict__ te_out)
{
    const int bb0 = blockIdx.x * 16;
    const int tid = threadIdx.x;
    const int w   = tid >> 6;      // 0..7
    const int l   = tid & 63;
    const int lg  = l >> 4;
    const int ln  = l & 15;
    const int rh  = w >> 2;        // GEMM1 row-half (0/1)
    const int wc  = w & 3;         // GEMM1 col-group

    __shared__ __align__(16) short flat_s[2][64 * 256];  // 2 x 32 KB, swizzled
    __shared__ __align__(16) short h_s[64 * 192];        // 24 KB, swizzled
    __shared__ float msk_s[16][64];                      // 4 KB
    __shared__ float ncol_s[16];
    __shared__ float csum_s[16][128];                    // 8 KB
    __shared__ float redq[2][16];

    // ---- pinned weights: W1 (96) + bias1 (12) + W2 (24) + bias2 (4)
    bf16x8 bw1[3][8];
    float  bias1[3][4];
    #pragma unroll
    for (int ct = 0; ct < 3; ++ct) {
        int j = wc * 48 + ct * 16 + ln;
        #pragma unroll
        for (int ks = 0; ks < 8; ++ks)
            bw1[ct][ks] = *(const bf16x8*)&W1T[j * 256 + ks * 32 + lg * 8];
        #pragma unroll
        for (int reg = 0; reg < 4; ++reg)
            bias1[ct][reg] = b1[wc * 48 + ct * 16 + lg * 4 + reg];
    }
    bf16x8 w2p[6];
    #pragma unroll
    for (int ks = 0; ks < 6; ++ks)
        w2p[ks] = *(const bf16x8*)&W2T[(w * 16 + ln) * 192 + ks * 32 + lg * 8];
    float bias2[4];
    #pragma unroll
    for (int reg = 0; reg < 4; ++reg) bias2[reg] = b2[w * 16 + lg * 4 + reg];
    #pragma unroll
    for (int ct = 0; ct < 3; ++ct) {
        #pragma unroll
        for (int ks = 0; ks < 8; ++ks) KEEP(bw1[ct][ks]);
        #pragma unroll
        for (int reg = 0; reg < 4; ++reg) KEEP(bias1[ct][reg]);
    }
    #pragma unroll
    for (int ks = 0; ks < 6; ++ks) KEEP(w2p[ks]);
    #pragma unroll
    for (int reg = 0; reg < 4; ++reg) KEEP(bias2[reg]);

    // ---- preload masks + num_cols for the 16 b's
    *(float2*)&((float*)msk_s)[tid * 2] =
        *(const float2*)&masks[(size_t)bb0 * C_ + tid * 2];
    if (tid < 16) ncol_s[tid] = (float)num_cols[bb0 + tid];

    // ---- depth-1 register prefetch: 8 float4/thread = one 64-row fp32 b
    float4 pf[8];
    auto issue = [&](int b) {
        #pragma unroll
        for (int i = 0; i < 8; ++i) {
            int slot = i * 512 + tid;        // 0..4095 float4 slots
            int r    = slot >> 6;            // 0..63
            int c    = slot & 63;
            const float* src = (c < 32)
                ? &header[((size_t)(bb0 + b) * C_ + r) * D_ + c * 4]
                : &tword [((size_t)(bb0 + b) * C_ + r) * D_ + (c - 32) * 4];
            pf[i] = *(const float4*)src;
        }
    };
    auto stage_write = [&](char* fbuf) {
        #pragma unroll
        for (int i = 0; i < 8; ++i) {
            int slot = i * 512 + tid;
            int r    = slot >> 6;
            int c    = slot & 63;
            uint2 p;
            p.x = cvt_pk_bf16(pf[i].x, pf[i].y);
            p.y = cvt_pk_bf16(pf[i].z, pf[i].w);
            *(uint2*)(fbuf + r * 512 + ((c * 8) ^ ((r & 7) << 4))) = p;
        }
    };

    issue(0);
    stage_write((char*)flat_s[0]);   // vmcnt wait for pf(0) happens here
    issue(1);
    __syncthreads();                 // flat(0) + masks visible (prologue only)

    float csum[4] = {0.f, 0.f, 0.f, 0.f};

    #pragma unroll 1
    for (int b = 0; b < 16; ++b) {
        char* fbuf = (char*)flat_s[b & 1];

        // ---- GEMM1: rows rh*32 + rt*16 + ln, cols wc*48..+48 (48 MFMA)
        #pragma unroll
        for (int rt = 0; rt < 2; ++rt) {
            int row = rh * 32 + rt * 16 + ln;
            int sz  = (row & 7) << 4;
            f32x4 acc[3];
            #pragma unroll
            for (int ct = 0; ct < 3; ++ct)
                acc[ct] = (f32x4){bias1[ct][0], bias1[ct][1], bias1[ct][2], bias1[ct][3]};
            #pragma unroll
            for (int ks = 0; ks < 8; ++ks) {
                bf16x8 xf = *(const bf16x8*)(fbuf + row * 512 + ((ks * 64 + lg * 16) ^ sz));
                #pragma unroll
                for (int ct = 0; ct < 3; ++ct)
                    acc[ct] = __builtin_amdgcn_mfma_f32_16x16x32_bf16(bw1[ct][ks], xf, acc[ct], 0, 0, 0);
            }
            #pragma unroll
            for (int ct = 0; ct < 3; ++ct) {
                int col0 = wc * 48 + ct * 16 + lg * 4;
                uint2 hp;
                hp.x = cvt_pk_bf16(fmaxf(acc[ct][0], 0.f), fmaxf(acc[ct][1], 0.f));
                hp.y = cvt_pk_bf16(fmaxf(acc[ct][2], 0.f), fmaxf(acc[ct][3], 0.f));
                *(uint2*)((char*)h_s + row * 384 + ((col0 * 2) ^ sz)) = hp;
            }
        }

        // ---- stage next b from pf; refill pf one further ahead
        if (b < 15) {
            stage_write((char*)flat_s[(b + 1) & 1]);
            if (b < 14) issue(b + 2);
        }
        wg_barrier();   // A: h(b) + flat(b+1) ready; pf loads stay in flight

        // ---- GEMM2: wave w owns j2 = w*16..+16, full K (24 MFMA) + csum
        #pragma unroll
        for (int rt = 0; rt < 4; ++rt) {
            int row = rt * 16 + ln;
            int sz  = (row & 7) << 4;
            f32x4 acc2 = (f32x4){bias2[0], bias2[1], bias2[2], bias2[3]};
            #pragma unroll
            for (int ks = 0; ks < 6; ++ks) {
                bf16x8 hf = *(const bf16x8*)((char*)h_s + row * 384 + ((ks * 64 + lg * 16) ^ sz));
                acc2 = __builtin_amdgcn_mfma_f32_16x16x32_bf16(w2p[ks], hf, acc2, 0, 0, 0);
            }
            float m = msk_s[b][row];
            #pragma unroll
            for (int reg = 0; reg < 4; ++reg)
                csum[reg] = fmaf(fmaxf(acc2[reg], 0.f), m, csum[reg]);
        }

        // ---- per-b flush: butterfly over ln, barrier-free LDS write
        #pragma unroll
        for (int s = 1; s < 16; s <<= 1)
            #pragma unroll
            for (int reg = 0; reg < 4; ++reg)
                csum[reg] += __shfl_xor(csum[reg], s, 64);
        if (ln == 0) {
            #pragma unroll
            for (int reg = 0; reg < 4; ++reg)
                csum_s[b][w * 16 + lg * 4 + reg] = csum[reg];
        }
        #pragma unroll
        for (int reg = 0; reg < 4; ++reg) csum[reg] = 0.f;

        wg_barrier();   // B: GEMM2 h-reads done before GEMM1(b+1) overwrites h
    }

    // ---- epilogue: /num_cols, l2norm, store for all 16 b's
    float vv[16];
    if (tid < 128) {
        #pragma unroll
        for (int bi = 0; bi < 16; ++bi) {
            float v = csum_s[bi][tid] / ncol_s[bi];
            vv[bi] = v;
            float s2 = v * v;
            #pragma unroll
            for (int sh = 1; sh < 64; sh <<= 1) s2 += __shfl_xor(s2, sh, 64);
            if (l == 0) redq[w][bi] = s2;
        }
    }
    __syncthreads();
    if (tid < 128) {
        #pragma unroll
        for (int bi = 0; bi < 16; ++bi) {
            float inv = rsqrtf(fmaxf(redq[0][bi] + redq[1][bi], 1e-12f));
            te_out[(size_t)(bb0 + bi) * D_ + tid] = vv[bi] * inv;
        }
    }
}

// ---------------------------------------------------------------------------
// LSTM (round-5 structure, unchanged): 256 blocks x 512 threads, 16 rows/blk.
// ---------------------------------------------------------------------------
__global__ __launch_bounds__(512) __attribute__((amdgpu_waves_per_eu(1, 2)))
void lstm_kernel(
    const float* __restrict__ q, const int* __restrict__ lengths,
    const short* __restrict__ WTl, const float* __restrict__ bl,
    float* __restrict__ qe_out)
{
    const int tid = threadIdx.x;
    const int b0  = blockIdx.x * 16;
    const int w   = tid >> 6;
    const int l   = tid & 63;
    const int lg  = l >> 4;
    const int ln  = l & 15;       // batch row within block
    const int d0  = w * 16 + lg * 4;

    __shared__ __align__(16) short xh[2][16 * 256];  // 2 x 8 KB, swizzled
    __shared__ float red8[8][16];

    bf16x8 wf[4][8];
    #pragma unroll
    for (int g = 0; g < 4; ++g)
        #pragma unroll
        for (int ks = 0; ks < 8; ++ks)
            wf[g][ks] = *(const bf16x8*)&WTl[(w * 64 + g * 16 + ln) * 256 + ks * 32 + lg * 8];
    float bias[4][4];
    #pragma unroll
    for (int g = 0; g < 4; ++g)
        #pragma unroll
        for (int reg = 0; reg < 4; ++reg)
            bias[g][reg] = bl[g * 128 + d0 + reg];
    #pragma unroll
    for (int g = 0; g < 4; ++g) {
        #pragma unroll
        for (int ks = 0; ks < 8; ++ks) KEEP(wf[g][ks]);
        #pragma unroll
        for (int reg = 0; reg < 4; ++reg) KEEP(bias[g][reg]);
    }

    float creg[4] = {0.f, 0.f, 0.f, 0.f};
    float hreg[4] = {0.f, 0.f, 0.f, 0.f};
    const int len = lengths[b0 + ln];
    const int sr = tid >> 5, sc = tid & 31;

    // prefetch x_0
    float4 qv = *(const float4*)&q[((size_t)(b0 + sr) * LQ_ + 0) * D_ + sc * 4];

    for (int t = 0; t < LQ_; ++t) {
        char* buf = (char*)xh[t & 1];
        uint2 px; px.x = cvt_pk_bf16(qv.x, qv.y); px.y = cvt_pk_bf16(qv.z, qv.w);
        *(uint2*)(buf + sr * 512 + ((sc * 8) ^ ((sr & 7) << 4))) = px;
        uint2 ph; ph.x = cvt_pk_bf16(hreg[0], hreg[1]); ph.y = cvt_pk_bf16(hreg[2], hreg[3]);
        *(uint2*)(buf + ln * 512 + ((256 + d0 * 2) ^ ((ln & 7) << 4))) = ph;
        if (t + 1 < LQ_)
            qv = *(const float4*)&q[((size_t)(b0 + sr) * LQ_ + (t + 1)) * D_ + sc * 4];
        wg_barrier();

        f32x4 acc[4];
        #pragma unroll
        for (int g = 0; g < 4; ++g)
            acc[g] = (f32x4){bias[g][0], bias[g][1], bias[g][2], bias[g][3]};
        #pragma unroll
        for (int ks = 0; ks < 8; ++ks) {
            bf16x8 xf = *(const bf16x8*)(buf + ln * 512 + ((ks * 64 + lg * 16) ^ ((ln & 7) << 4)));
            #pragma unroll
            for (int g = 0; g < 4; ++g)
                acc[g] = __builtin_amdgcn_mfma_f32_16x16x32_bf16(wf[g][ks], xf, acc[g], 0, 0, 0);
        }

        bool live = (t < len);
        #pragma unroll
        for (int reg = 0; reg < 4; ++reg) {
            float iv = sigm(acc[0][reg]);
            float fv = sigm(acc[1][reg]);
            float gv = fmaxf(acc[2][reg], 0.f);
            float ov = sigm(acc[3][reg]);
            float cn = fmaf(fv, creg[reg], iv * gv);
            float hn = ov * fmaxf(cn, 0.f);
            if (live) { creg[reg] = cn; hreg[reg] = hn; }
        }
    }

    float sq = 0.f;
    #pragma unroll
    for (int reg = 0; reg < 4; ++reg) sq = fmaf(hreg[reg], hreg[reg], sq);
    sq += __shfl_xor(sq, 16, 64);
    sq += __shfl_xor(sq, 32, 64);
    if (l < 16) red8[w][ln] = sq;
    wg_barrier();
    float tot = 0.f;
    #pragma unroll
    for (int ww = 0; ww < 8; ++ww) tot += red8[ww][ln];
    float inv = rsqrtf(fmaxf(tot, 1e-12f));
    float4 o;
    o.x = hreg[0] * inv; o.y = hreg[1] * inv; o.z = hreg[2] * inv; o.w = hreg[3] * inv;
    *(float4*)&qe_out[(size_t)(b0 + ln) * D_ + d0] = o;
}

// ---------------------------------------------------------------------------
// Loss: 64 blocks x 64 threads, 1 sample per thread.
// ---------------------------------------------------------------------------
__global__ __launch_bounds__(64) void loss_kernel(
    const float* __restrict__ te, const float* __restrict__ qe,
    const float* __restrict__ labels, float* __restrict__ partial)
{
    const int tid = threadIdx.x;
    const int b   = blockIdx.x * 64 + tid;
    float dsum = 0.f;
    #pragma unroll 8
    for (int k4 = 0; k4 < 32; ++k4) {
        float4 a = *(const float4*)&qe[(size_t)b * D_ + k4 * 4];
        float4 c = *(const float4*)&te[(size_t)b * D_ + k4 * 4];
        float dx = a.x - c.x, dy = a.y - c.y, dz = a.z - c.z, dw = a.w - c.w;
        dsum += dx * dx + dy * dy + dz * dz + dw * dw;
    }
    float lab = labels[b];
    float ds  = sqrtf(dsum);
    float ml  = fmaxf(0.f, 1.f - ds);
    float loss = lab * dsum + (1.f - lab) * ml * ml;
    #pragma unroll
    for (int s = 32; s > 0; s >>= 1) loss += __shfl_xor(loss, s, 64);
    if (tid == 0) partial[blockIdx.x] = loss;
}

__global__ void final_kernel(const float* __restrict__ partial, float* __restrict__ out)
{
    const int tid = threadIdx.x;   // 64 threads
    float v = partial[tid];
    #pragma unroll
    for (int s = 32; s > 0; s >>= 1) v += __shfl_xor(v, s, 64);
    if (tid == 0) out[0] = 0.5f * v / (float)B_;
}

// ---------------------------------------------------------------------------
extern "C" void kernel_launch(void* const* d_in, const int* in_sizes, int n_in,
                              void* d_out, int out_size, void* d_ws, size_t ws_size,
                              hipStream_t stream)
{
    const float* q      = (const float*)d_in[0];
    const int*   qlen   = (const int*)d_in[1];
    const float* header = (const float*)d_in[2];
    const float* tword  = (const float*)d_in[3];
    const int*   ncols  = (const int*)d_in[4];
    const float* masks  = (const float*)d_in[5];
    const float* labels = (const float*)d_in[6];
    const float* W1     = (const float*)d_in[7];
    const float* b1     = (const float*)d_in[8];
    const float* W2     = (const float*)d_in[9];
    const float* b2     = (const float*)d_in[10];
    const float* Wx     = (const float*)d_in[11];
    const float* Wh     = (const float*)d_in[12];
    const float* bl     = (const float*)d_in[13];
    float* out = (float*)d_out;

    float* te      = (float*)d_ws;
    float* qe      = te + (size_t)B_ * D_;
    float* partial = qe + (size_t)B_ * D_;
    short* W1T     = (short*)(partial + 64);          // 192*256
    short* W2T     = W1T + 192 * 256;                 // 128*192
    short* WTl     = W2T + 128 * 192;                 // 512*256

    prep_kernel<<<512, 256, 0, stream>>>(W1, W2, Wx, Wh, W1T, W2T, WTl);
    table_kernel<<<B_ / 16, 512, 0, stream>>>(header, tword, masks, ncols, W1T, b1, W2T, b2, te);
    lstm_kernel<<<B_ / 16, 512, 0, stream>>>(q, qlen, WTl, bl, qe);
    loss_kernel<<<B_ / 64, 64, 0, stream>>>(te, qe, labels, partial);
    final_kernel<<<1, 64, 0, stream>>>(partial, out);
}